// Round 1
// baseline (852.570 us; speedup 1.0000x reference)
//
#include <hip/hip_runtime.h>
#include <math.h>

#define BB 32
#define SS 2048
#define HH 1024
#define VV 2048  // 2*H

// tanh(x) = 1 - 2/(exp(2x)+1). Saturates cleanly: x->+inf => 1, x->-inf => -1.
__device__ __forceinline__ float fast_tanh(float x) {
    float e = __expf(2.0f * x);
    return 1.0f - 2.0f * __builtin_amdgcn_rcpf(e + 1.0f);
}

__device__ __forceinline__ float wave_reduce_sum(float v) {
#pragma unroll
    for (int off = 32; off > 0; off >>= 1)
        v += __shfl_xor(v, off, 64);
    return v;
}

// K1: pq[b,k] = sum_h query[b,h]*Wq[k,h] + bq[k]
// grid = 1024 (one wave per k), block = 64
__global__ __launch_bounds__(64) void k1_proj_query(
    const float* __restrict__ query, const float* __restrict__ Wq,
    const float* __restrict__ bq, float* __restrict__ pq) {
    const int k = blockIdx.x;
    const int lane = threadIdx.x;
    float4 w[4];
#pragma unroll
    for (int j = 0; j < 4; j++)
        w[j] = *(const float4*)(Wq + (size_t)k * HH + lane * 4 + j * 256);
    const float bqk = bq[k];
    for (int b = 0; b < BB; b++) {
        float acc = 0.0f;
#pragma unroll
        for (int j = 0; j < 4; j++) {
            float4 q = *(const float4*)(query + (size_t)b * HH + lane * 4 + j * 256);
            acc = fmaf(w[j].x, q.x, acc);
            acc = fmaf(w[j].y, q.y, acc);
            acc = fmaf(w[j].z, q.z, acc);
            acc = fmaf(w[j].w, q.w, acc);
        }
        acc = wave_reduce_sum(acc);
        if (lane == 0) pq[b * HH + k] = acc + bqk;
    }
}

// K2: energy[b,s] = sum_h tanh(pq[b,h] + proj_key[b,s,h]) * v_energy[h], masked.
// grid = 32*16 = 512 blocks, block = 256 (4 waves); each wave does 32 s.
__global__ __launch_bounds__(256) void k2_energy(
    const float* __restrict__ proj_key, const float* __restrict__ pq,
    const float* __restrict__ v_energy, const int* __restrict__ src_mask,
    float* __restrict__ energy) {
    const int b = blockIdx.x >> 4;
    const int chunk = blockIdx.x & 15;
    const int wave = threadIdx.x >> 6;
    const int lane = threadIdx.x & 63;

    float4 p[4], ve[4];
#pragma unroll
    for (int j = 0; j < 4; j++) {
        p[j]  = *(const float4*)(pq + (size_t)b * HH + lane * 4 + j * 256);
        ve[j] = *(const float4*)(v_energy + lane * 4 + j * 256);
    }
    const int s0 = chunk * 128 + wave * 32;
    for (int i = 0; i < 32; i++) {
        const int s = s0 + i;
        const float* row = proj_key + ((size_t)b * SS + s) * HH;
        float acc = 0.0f;
#pragma unroll
        for (int j = 0; j < 4; j++) {
            float4 pk = *(const float4*)(row + lane * 4 + j * 256);
            acc = fmaf(fast_tanh(p[j].x + pk.x), ve[j].x, acc);
            acc = fmaf(fast_tanh(p[j].y + pk.y), ve[j].y, acc);
            acc = fmaf(fast_tanh(p[j].z + pk.z), ve[j].z, acc);
            acc = fmaf(fast_tanh(p[j].w + pk.w), ve[j].w, acc);
        }
        acc = wave_reduce_sum(acc);
        if (lane == 0) {
            float e = (src_mask[b * SS + s] == 0) ? -INFINITY : acc;
            energy[b * SS + s] = e;
        }
    }
}

// K3: alphas[b,:] = softmax(energy[b,:]). grid = 32, block = 256 (8 vals/thread).
__global__ __launch_bounds__(256) void k3_softmax(
    const float* __restrict__ energy, float* __restrict__ alphas) {
    const int b = blockIdx.x;
    const int t = threadIdx.x;
    const int wave = t >> 6;
    const int lane = t & 63;
    __shared__ float red[4];

    float vals[8];
    float m = -INFINITY;
#pragma unroll
    for (int i = 0; i < 8; i++) {
        vals[i] = energy[b * SS + t + i * 256];
        m = fmaxf(m, vals[i]);
    }
#pragma unroll
    for (int off = 32; off > 0; off >>= 1)
        m = fmaxf(m, __shfl_xor(m, off, 64));
    if (lane == 0) red[wave] = m;
    __syncthreads();
    m = fmaxf(fmaxf(red[0], red[1]), fmaxf(red[2], red[3]));
    __syncthreads();

    float sum = 0.0f;
#pragma unroll
    for (int i = 0; i < 8; i++) {
        vals[i] = __expf(vals[i] - m);
        sum += vals[i];
    }
    sum = wave_reduce_sum(sum);
    if (lane == 0) red[wave] = sum;
    __syncthreads();
    sum = red[0] + red[1] + red[2] + red[3];
    const float inv = 1.0f / sum;
#pragma unroll
    for (int i = 0; i < 8; i++)
        alphas[b * SS + t + i * 256] = vals[i] * inv;
}

// K4: partial context. grid = 32*16 = 512 blocks (b, s-chunk of 128), block = 256.
// Thread t accumulates v = t*4..t*4+3 and v = 1024+t*4..+3 (fully coalesced float4).
__global__ __launch_bounds__(256) void k4_context_partial(
    const float* __restrict__ value, const float* __restrict__ energy,
    float* __restrict__ part) {
    const int b = blockIdx.x >> 4;
    const int chunk = blockIdx.x & 15;
    const int t = threadIdx.x;
    __shared__ float se[128];
    if (t < 128) se[t] = energy[b * SS + chunk * 128 + t];
    __syncthreads();
    const float* vbase = value + ((size_t)b * SS + chunk * 128) * VV;
    float4 a0 = make_float4(0.f, 0.f, 0.f, 0.f);
    float4 a1 = make_float4(0.f, 0.f, 0.f, 0.f);
    for (int s = 0; s < 128; s++) {
        const float e = se[s];
        float4 x0 = *(const float4*)(vbase + (size_t)s * VV + t * 4);
        float4 x1 = *(const float4*)(vbase + (size_t)s * VV + 1024 + t * 4);
        a0.x = fmaf(e, x0.x, a0.x); a0.y = fmaf(e, x0.y, a0.y);
        a0.z = fmaf(e, x0.z, a0.z); a0.w = fmaf(e, x0.w, a0.w);
        a1.x = fmaf(e, x1.x, a1.x); a1.y = fmaf(e, x1.y, a1.y);
        a1.z = fmaf(e, x1.z, a1.z); a1.w = fmaf(e, x1.w, a1.w);
    }
    float* p = part + (size_t)blockIdx.x * VV;
    *(float4*)(p + t * 4) = a0;
    *(float4*)(p + 1024 + t * 4) = a1;
}

// K5: context[b,v] = sum over 16 s-chunk partials. grid = 64, block = 256.
__global__ __launch_bounds__(256) void k5_reduce(
    const float* __restrict__ part, float* __restrict__ context) {
    const int idx = blockIdx.x * 256 + threadIdx.x;  // 0..16383
    const int o = idx * 4;                            // element offset into (B*VV)
    const int b = o >> 11;                            // /2048
    const int v = o & 2047;
    float4 acc = make_float4(0.f, 0.f, 0.f, 0.f);
#pragma unroll
    for (int c = 0; c < 16; c++) {
        float4 x = *(const float4*)(part + ((size_t)(b * 16 + c)) * VV + v);
        acc.x += x.x; acc.y += x.y; acc.z += x.z; acc.w += x.w;
    }
    *(float4*)(context + o) = acc;
}

extern "C" void kernel_launch(void* const* d_in, const int* in_sizes, int n_in,
                              void* d_out, int out_size, void* d_ws, size_t ws_size,
                              hipStream_t stream) {
    const float* query    = (const float*)d_in[0];
    const float* proj_key = (const float*)d_in[1];
    const float* value    = (const float*)d_in[2];
    const int*   src_mask = (const int*)d_in[3];
    const float* Wq       = (const float*)d_in[4];
    const float* bq       = (const float*)d_in[5];
    const float* v_energy = (const float*)d_in[6];

    float* out     = (float*)d_out;
    float* context = out;                 // B*VV = 65536 floats
    float* alphas  = out + BB * VV;       // B*SS = 65536 floats

    char* ws = (char*)d_ws;
    float* pq     = (float*)ws;                         // 32*1024*4   = 128 KiB
    float* energy = (float*)(ws + (128 << 10));         // 32*2048*4   = 256 KiB
    float* part   = (float*)(ws + (128 << 10) + (256 << 10)); // 512*2048*4 = 4 MiB

    k1_proj_query<<<1024, 64, 0, stream>>>(query, Wq, bq, pq);
    k2_energy<<<512, 256, 0, stream>>>(proj_key, pq, v_energy, src_mask, energy);
    k3_softmax<<<32, 256, 0, stream>>>(energy, alphas);
    k4_context_partial<<<512, 256, 0, stream>>>(value, energy, part);
    k5_reduce<<<64, 256, 0, stream>>>(part, context);
}